// Round 9
// baseline (643.746 us; speedup 1.0000x reference)
//
#include <hip/hip_runtime.h>

#define NN 10000
#define NE 640000
#define CH 128
#define NH 8
#define HD 16
#define BD 32
#define NEG 0.01f

#define PROJ_BLOCKS (NN / 16)            // 625
#define HIST_BLOCKS ((NE + 255) / 256)   // 2500

__device__ __forceinline__ float rdlane(float v, int idx) {
    return __int_as_float(__builtin_amdgcn_readlane(__float_as_int(v), idx));
}

// DPP butterfly sum over each 16-lane row (one head = 16 channels): pure VALU.
template <int CTRL>
__device__ __forceinline__ float dpp_add(float x) {
    int v = __builtin_amdgcn_update_dpp(0, __float_as_int(x), CTRL, 0xF, 0xF, true);
    return x + __int_as_float(v);
}
__device__ __forceinline__ float sum16(float x) {
    x = dpp_add<0xB1>(x);   // quad_perm xor1
    x = dpp_add<0x4E>(x);   // quad_perm xor2
    x = dpp_add<0x141>(x);  // row_half_mirror
    x = dpp_add<0x140>(x);  // row_mirror
    return x;
}

// ---------------- proj + hist fused (independent work, concurrent blocks) ----
__device__ void proj_body(
    int blk, const float* __restrict__ senders, const float* __restrict__ receivers,
    const float* __restrict__ WQ, const float* __restrict__ WK,
    const float* __restrict__ WV,
    float* __restrict__ Qn, float2* __restrict__ KVn)
{
    int wave = threadIdx.x >> 6, l = threadIdx.x & 63;
    int n0 = (blk * 4 + wave) * 4;
    float r0[4], r1[4], s0[4], s1[4];
#pragma unroll
    for (int i = 0; i < 4; ++i) {
        r0[i] = receivers[(size_t)(n0 + i) * CH + l];
        r1[i] = receivers[(size_t)(n0 + i) * CH + 64 + l];
        s0[i] = senders[(size_t)(n0 + i) * CH + l];
        s1[i] = senders[(size_t)(n0 + i) * CH + 64 + l];
    }
    float q0[4] = {0,0,0,0}, q1[4] = {0,0,0,0};
    float k0[4] = {0,0,0,0}, k1[4] = {0,0,0,0};
    float v0[4] = {0,0,0,0}, v1[4] = {0,0,0,0};
    for (int ln = 0; ln < 64; ++ln) {
        float wq0 = WQ[ln * CH + l], wq1 = WQ[ln * CH + 64 + l];
        float wk0 = WK[ln * CH + l], wk1 = WK[ln * CH + 64 + l];
        float wv0 = WV[ln * CH + l], wv1 = WV[ln * CH + 64 + l];
#pragma unroll
        for (int i = 0; i < 4; ++i) {
            float rv = rdlane(r0[i], ln);
            float sv = rdlane(s0[i], ln);
            q0[i] = fmaf(rv, wq0, q0[i]);  q1[i] = fmaf(rv, wq1, q1[i]);
            k0[i] = fmaf(sv, wk0, k0[i]);  k1[i] = fmaf(sv, wk1, k1[i]);
            v0[i] = fmaf(sv, wv0, v0[i]);  v1[i] = fmaf(sv, wv1, v1[i]);
        }
    }
    for (int ln = 0; ln < 64; ++ln) {
        int kk = 64 + ln;
        float wq0 = WQ[kk * CH + l], wq1 = WQ[kk * CH + 64 + l];
        float wk0 = WK[kk * CH + l], wk1 = WK[kk * CH + 64 + l];
        float wv0 = WV[kk * CH + l], wv1 = WV[kk * CH + 64 + l];
#pragma unroll
        for (int i = 0; i < 4; ++i) {
            float rv = rdlane(r1[i], ln);
            float sv = rdlane(s1[i], ln);
            q0[i] = fmaf(rv, wq0, q0[i]);  q1[i] = fmaf(rv, wq1, q1[i]);
            k0[i] = fmaf(sv, wk0, k0[i]);  k1[i] = fmaf(sv, wk1, k1[i]);
            v0[i] = fmaf(sv, wv0, v0[i]);  v1[i] = fmaf(sv, wv1, v1[i]);
        }
    }
#pragma unroll
    for (int i = 0; i < 4; ++i) {
        size_t o = (size_t)(n0 + i) * CH;
        Qn[o + l] = q0[i];
        Qn[o + 64 + l] = q1[i];
        KVn[o + l] = make_float2(k0[i], v0[i]);
        KVn[o + 64 + l] = make_float2(k1[i], v1[i]);
    }
}

__global__ __launch_bounds__(256) void proj_hist_kernel(
    const float* __restrict__ senders, const float* __restrict__ receivers,
    const float* __restrict__ WQ, const float* __restrict__ WK,
    const float* __restrict__ WV,
    float* __restrict__ Qn, float2* __restrict__ KVn,
    const int* __restrict__ eidx, int* __restrict__ counts,
    int* __restrict__ rank)
{
    if (blockIdx.x < PROJ_BLOCKS) {
        proj_body(blockIdx.x, senders, receivers, WQ, WK, WV, Qn, KVn);
    } else {
        int e = (blockIdx.x - PROJ_BLOCKS) * 256 + threadIdx.x;
        if (e < NE) rank[e] = atomicAdd(&counts[eidx[NE + e]], 1);
    }
}

// ---------------- prefix scan (single block) ---------------------------------
__global__ __launch_bounds__(1024) void scan_kernel(
    const int* __restrict__ counts, int* __restrict__ starts)
{
    __shared__ int s[1024];
    int tid = threadIdx.x;
    const int CHUNK = 10;  // 1024*10 >= NN
    int base = tid * CHUNK;
    int local = 0;
    for (int i = base; i < base + CHUNK && i < NN; ++i) local += counts[i];
    s[tid] = local;
    __syncthreads();
    for (int off = 1; off < 1024; off <<= 1) {
        int t = (tid >= off) ? s[tid - off] : 0;
        __syncthreads();
        s[tid] += t;
        __syncthreads();
    }
    int run = s[tid] - local;
    for (int i = base; i < base + CHUNK && i < NN; ++i) {
        starts[i] = run;
        run += counts[i];
    }
    if (tid == 1023) starts[NN] = s[1023];
}

// ---------------- scatter: one int2 {edge, src} per slot ---------------------
__global__ void scatter_kernel(const int* __restrict__ eidx,
                               const int* __restrict__ rank,
                               const int* __restrict__ starts,
                               int2* __restrict__ es)
{
    int e = blockIdx.x * blockDim.x + threadIdx.x;
    if (e < NE) {
        int p = starts[eidx[NE + e]] + rank[e];
        es[p] = make_int2(e, eidx[e]);
    }
}

// ---------------- fused per-node edge loop -----------------------------------
// One WAVE per node (R6's best layout; lane l owns channels l and l+64).
// 8-edge tiles. eattr enters through ONE vector dwordx4 per lane per tile
// (lane l -> row l>>3, floats (l&7)*4..+3) and is broadcast with v_readlane:
// no scalar-memory latency chain (R8's failure) and no LDS (R3's failure).
// W is amortized 8x by k-chunking (8 L1-hot vector loads per chunk of 8 k).
__global__ __launch_bounds__(256, 4) void fused_kernel(
    const int2* __restrict__ es, const int* __restrict__ starts,
    const float* __restrict__ eattr, const float* __restrict__ WE,
    const float* __restrict__ att, const float* __restrict__ Qn,
    const float2* __restrict__ KVn, float* __restrict__ out)
{
    int wave = threadIdx.x >> 6, l = threadIdx.x & 63;
    int n = blockIdx.x * 4 + wave;            // 2500 blocks * 4 waves = NN
    int start = starts[n], end = starts[n + 1];

    float a0 = att[l], a1 = att[64 + l];
    float q0 = Qn[(size_t)n * CH + l], q1 = Qn[(size_t)n * CH + 64 + l];
    float acc0 = 0.f, acc1 = 0.f, sum0 = 0.f, sum1 = 0.f;

    for (int base = start; base < end; base += 8) {
        int m = end - base;                   // may exceed 8 (full tile)
        int idx = base + (l >> 3);
        if (idx >= end) idx = end - 1;        // clamp: duplicate rows, masked later
        int2 esv = es[idx];                   // lane l: edge for row l>>3
        float4 ea4 = *(const float4*)(eattr + (size_t)esv.x * BD + ((l & 7) << 2));
        float eaa[4] = {ea4.x, ea4.y, ea4.z, ea4.w};

        float ec0[8] = {0,0,0,0,0,0,0,0};
        float ec1[8] = {0,0,0,0,0,0,0,0};
#pragma unroll
        for (int kc = 0; kc < 4; ++kc) {
            float w0[8], w1[8];
#pragma unroll
            for (int kk = 0; kk < 8; ++kk) {
                w0[kk] = WE[(kc * 8 + kk) * CH + l];
                w1[kk] = WE[(kc * 8 + kk) * CH + 64 + l];
            }
#pragma unroll
            for (int t = 0; t < 8; ++t) {
#pragma unroll
                for (int kk = 0; kk < 8; ++kk) {
                    int k = kc * 8 + kk;
                    // row t's k-th float lives in lane t*8 + (k>>2), comp k&3
                    float v = rdlane(eaa[k & 3], t * 8 + (k >> 2));
                    ec0[t] = fmaf(v, w0[kk], ec0[t]);
                    ec1[t] = fmaf(v, w1[kk], ec1[t]);
                }
            }
        }
#pragma unroll 8
        for (int t = 0; t < 8; ++t) {
            if (t >= m) break;                // wave-uniform
            int src = __builtin_amdgcn_readlane(esv.y, t * 8);
            const float2* __restrict__ kvrow = KVn + (size_t)src * CH;
            float2 kv0 = kvrow[l];
            float2 kv1 = kvrow[64 + l];
            float h0 = q0 + kv0.x + ec0[t]; h0 = h0 > 0.f ? h0 : NEG * h0;
            float h1 = q1 + kv1.x + ec1[t]; h1 = h1 > 0.f ? h1 : NEG * h1;
            float p0 = __expf(sum16(a0 * h0));
            float p1 = __expf(sum16(a1 * h1));
            sum0 += p0; acc0 = fmaf(p0, kv0.y, acc0);
            sum1 += p1; acc1 = fmaf(p1, kv1.y, acc1);
        }
    }
    out[(size_t)n * CH + l]      = (end > start) ? acc0 / sum0 : 0.f;
    out[(size_t)n * CH + 64 + l] = (end > start) ? acc1 / sum1 : 0.f;
}

extern "C" void kernel_launch(void* const* d_in, const int* in_sizes, int n_in,
                              void* d_out, int out_size, void* d_ws, size_t ws_size,
                              hipStream_t stream)
{
    const float* senders   = (const float*)d_in[0];
    const float* receivers = (const float*)d_in[1];
    const int*   eidx      = (const int*)d_in[2];
    const float* eattr     = (const float*)d_in[3];
    const float* WQ  = (const float*)d_in[4];
    const float* WK  = (const float*)d_in[5];
    const float* WV  = (const float*)d_in[6];
    const float* WE  = (const float*)d_in[7];
    const float* att = (const float*)d_in[8];
    float* out = (float*)d_out;

    char* ws = (char*)d_ws;
    size_t off = 0;
    auto alloc = [&](size_t bytes) -> void* {
        void* p = ws + off;
        off += (bytes + 255) & ~(size_t)255;
        return p;
    };
    // Total ~23.2 MB (< 38.5 MB proven safe in R1; R2's 43.7 MB failed)
    float*  Qn     = (float*)alloc((size_t)NN * CH * 4);
    float2* KVn    = (float2*)alloc((size_t)NN * CH * 8);
    int*    counts = (int*)alloc((size_t)NN * 4);
    int*    starts = (int*)alloc((size_t)(NN + 1) * 4);
    int*    rank   = (int*)alloc((size_t)NE * 4);
    int2*   es     = (int2*)alloc((size_t)NE * 8);

    hipMemsetAsync(counts, 0, (size_t)NN * 4, stream);
    proj_hist_kernel<<<PROJ_BLOCKS + HIST_BLOCKS, 256, 0, stream>>>(
        senders, receivers, WQ, WK, WV, Qn, KVn, eidx, counts, rank);
    scan_kernel<<<1, 1024, 0, stream>>>(counts, starts);
    scatter_kernel<<<HIST_BLOCKS, 256, 0, stream>>>(eidx, rank, starts, es);
    fused_kernel<<<NN / 4, 256, 0, stream>>>(es, starts, eattr, WE, att, Qn, KVn, out);
}

// Round 10
// 345.945 us; speedup vs baseline: 1.8608x; 1.8608x over previous
//
#include <hip/hip_runtime.h>

#define NN 10000
#define NE 640000
#define CH 128
#define NH 8
#define HD 16
#define BD 32
#define NEG 0.01f

#define PROJ_BLOCKS (NN / 16)            // 625
#define HIST_BLOCKS ((NE + 255) / 256)   // 2500

__device__ __forceinline__ float rdlane(float v, int idx) {
    return __int_as_float(__builtin_amdgcn_readlane(__float_as_int(v), idx));
}

// bf16 round-to-nearest-even pack/unpack (K path only; error budget analysed:
// logit-side only, ~1e-3 output effect. V stays f32 - V-rounding would land
// ~7e-3, at the 8.4e-3 threshold).
__device__ __forceinline__ unsigned short bf16rne(float f) {
    unsigned b = __float_as_uint(f);
    b += 0x7fffu + ((b >> 16) & 1u);
    return (unsigned short)(b >> 16);
}
__device__ __forceinline__ float bf16up(unsigned short u) {
    return __uint_as_float((unsigned)u << 16);
}

// DPP butterfly sum over each 16-lane row (one head = 16 channels): pure VALU.
template <int CTRL>
__device__ __forceinline__ float dpp_add(float x) {
    int v = __builtin_amdgcn_update_dpp(0, __float_as_int(x), CTRL, 0xF, 0xF, true);
    return x + __int_as_float(v);
}
__device__ __forceinline__ float sum16(float x) {
    x = dpp_add<0xB1>(x);   // quad_perm xor1
    x = dpp_add<0x4E>(x);   // quad_perm xor2
    x = dpp_add<0x141>(x);  // row_half_mirror
    x = dpp_add<0x140>(x);  // row_mirror
    return x;
}

// ---------------- proj + hist fused (independent work, concurrent blocks) ----
__device__ void proj_body(
    int blk, const float* __restrict__ senders, const float* __restrict__ receivers,
    const float* __restrict__ WQ, const float* __restrict__ WK,
    const float* __restrict__ WV,
    float* __restrict__ Qn, unsigned short* __restrict__ KB,
    float* __restrict__ Vn)
{
    int wave = threadIdx.x >> 6, l = threadIdx.x & 63;
    int n0 = (blk * 4 + wave) * 4;
    float r0[4], r1[4], s0[4], s1[4];
#pragma unroll
    for (int i = 0; i < 4; ++i) {
        r0[i] = receivers[(size_t)(n0 + i) * CH + l];
        r1[i] = receivers[(size_t)(n0 + i) * CH + 64 + l];
        s0[i] = senders[(size_t)(n0 + i) * CH + l];
        s1[i] = senders[(size_t)(n0 + i) * CH + 64 + l];
    }
    float q0[4] = {0,0,0,0}, q1[4] = {0,0,0,0};
    float k0[4] = {0,0,0,0}, k1[4] = {0,0,0,0};
    float v0[4] = {0,0,0,0}, v1[4] = {0,0,0,0};
    for (int ln = 0; ln < 64; ++ln) {
        float wq0 = WQ[ln * CH + l], wq1 = WQ[ln * CH + 64 + l];
        float wk0 = WK[ln * CH + l], wk1 = WK[ln * CH + 64 + l];
        float wv0 = WV[ln * CH + l], wv1 = WV[ln * CH + 64 + l];
#pragma unroll
        for (int i = 0; i < 4; ++i) {
            float rv = rdlane(r0[i], ln);
            float sv = rdlane(s0[i], ln);
            q0[i] = fmaf(rv, wq0, q0[i]);  q1[i] = fmaf(rv, wq1, q1[i]);
            k0[i] = fmaf(sv, wk0, k0[i]);  k1[i] = fmaf(sv, wk1, k1[i]);
            v0[i] = fmaf(sv, wv0, v0[i]);  v1[i] = fmaf(sv, wv1, v1[i]);
        }
    }
    for (int ln = 0; ln < 64; ++ln) {
        int kk = 64 + ln;
        float wq0 = WQ[kk * CH + l], wq1 = WQ[kk * CH + 64 + l];
        float wk0 = WK[kk * CH + l], wk1 = WK[kk * CH + 64 + l];
        float wv0 = WV[kk * CH + l], wv1 = WV[kk * CH + 64 + l];
#pragma unroll
        for (int i = 0; i < 4; ++i) {
            float rv = rdlane(r1[i], ln);
            float sv = rdlane(s1[i], ln);
            q0[i] = fmaf(rv, wq0, q0[i]);  q1[i] = fmaf(rv, wq1, q1[i]);
            k0[i] = fmaf(sv, wk0, k0[i]);  k1[i] = fmaf(sv, wk1, k1[i]);
            v0[i] = fmaf(sv, wv0, v0[i]);  v1[i] = fmaf(sv, wv1, v1[i]);
        }
    }
#pragma unroll
    for (int i = 0; i < 4; ++i) {
        size_t o = (size_t)(n0 + i) * CH;
        Qn[o + l] = q0[i];
        Qn[o + 64 + l] = q1[i];
        KB[o + l] = bf16rne(k0[i]);
        KB[o + 64 + l] = bf16rne(k1[i]);
        Vn[o + l] = v0[i];
        Vn[o + 64 + l] = v1[i];
    }
}

__global__ __launch_bounds__(256) void proj_hist_kernel(
    const float* __restrict__ senders, const float* __restrict__ receivers,
    const float* __restrict__ WQ, const float* __restrict__ WK,
    const float* __restrict__ WV,
    float* __restrict__ Qn, unsigned short* __restrict__ KB,
    float* __restrict__ Vn,
    const int* __restrict__ eidx, int* __restrict__ counts,
    int* __restrict__ rank)
{
    if (blockIdx.x < PROJ_BLOCKS) {
        proj_body(blockIdx.x, senders, receivers, WQ, WK, WV, Qn, KB, Vn);
    } else {
        int e = (blockIdx.x - PROJ_BLOCKS) * 256 + threadIdx.x;
        if (e < NE) rank[e] = atomicAdd(&counts[eidx[NE + e]], 1);
    }
}

// ---------------- prefix scan (single block) ---------------------------------
__global__ __launch_bounds__(1024) void scan_kernel(
    const int* __restrict__ counts, int* __restrict__ starts)
{
    __shared__ int s[1024];
    int tid = threadIdx.x;
    const int CHUNK = 10;  // 1024*10 >= NN
    int base = tid * CHUNK;
    int local = 0;
    for (int i = base; i < base + CHUNK && i < NN; ++i) local += counts[i];
    s[tid] = local;
    __syncthreads();
    for (int off = 1; off < 1024; off <<= 1) {
        int t = (tid >= off) ? s[tid - off] : 0;
        __syncthreads();
        s[tid] += t;
        __syncthreads();
    }
    int run = s[tid] - local;
    for (int i = base; i < base + CHUNK && i < NN; ++i) {
        starts[i] = run;
        run += counts[i];
    }
    if (tid == 1023) starts[NN] = s[1023];
}

// ---------------- scatter: one int2 {edge, src} per slot ---------------------
__global__ void scatter_kernel(const int* __restrict__ eidx,
                               const int* __restrict__ rank,
                               const int* __restrict__ starts,
                               int2* __restrict__ es)
{
    int e = blockIdx.x * blockDim.x + threadIdx.x;
    if (e < NE) {
        int p = starts[eidx[NE + e]] + rank[e];
        es[p] = make_int2(e, eidx[e]);
    }
}

// ---------------- fused per-node edge loop (R6 structure, verbatim) ----------
// One WAVE per node, lane l owns channels l and l+64. 8-edge tiles; eattr
// rows via wave-uniform s_load; K gathered as bf16 (halved K traffic, safe:
// logit-path only), V as f32. R8/R9 lessons: no k-chunked s_loads, no big
// per-tile register arrays (spill).
__global__ __launch_bounds__(256, 4) void fused_kernel(
    const int2* __restrict__ es, const int* __restrict__ starts,
    const float* __restrict__ eattr, const float* __restrict__ WE,
    const float* __restrict__ att, const float* __restrict__ Qn,
    const unsigned short* __restrict__ KB, const float* __restrict__ Vn,
    float* __restrict__ out)
{
    int wave = threadIdx.x >> 6, l = threadIdx.x & 63;
    int n = blockIdx.x * 4 + wave;            // 2500 blocks * 4 waves = NN
    int start = starts[n], end = starts[n + 1];

    float rWE[2 * BD];
#pragma unroll
    for (int k = 0; k < BD; ++k) {
        rWE[k]      = WE[k * CH + l];
        rWE[BD + k] = WE[k * CH + 64 + l];
    }
#pragma unroll
    for (int k = 0; k < 2 * BD; ++k) asm volatile("" : "+v"(rWE[k]));

    float a0 = att[l], a1 = att[64 + l];
    float q0 = Qn[(size_t)n * CH + l], q1 = Qn[(size_t)n * CH + 64 + l];
    float acc0 = 0.f, acc1 = 0.f, sum0 = 0.f, sum1 = 0.f;

    for (int base = start; base < end; base += 8) {
        int m = end - base;                   // >=1
        int idx = base + (l & 7);
        if (idx >= end) idx = end - 1;
        int2 esv = es[idx];
#pragma unroll 8
        for (int t = 0; t < 8; ++t) {
            if (t >= m) break;                // wave-uniform
            int e   = __builtin_amdgcn_readlane(esv.x, t);
            int src = __builtin_amdgcn_readlane(esv.y, t);
            const float* __restrict__ row = eattr + (size_t)e * BD;
            size_t so = (size_t)src * CH;
            float kb0 = bf16up(KB[so + l]);
            float kb1 = bf16up(KB[so + 64 + l]);
            float vv0 = Vn[so + l];
            float vv1 = Vn[so + 64 + l];
            float ec0 = 0.f, ec1 = 0.f;
#pragma unroll
            for (int k = 0; k < BD; ++k) {
                float rv = row[k];            // uniform -> s_load
                ec0 = fmaf(rv, rWE[k],      ec0);
                ec1 = fmaf(rv, rWE[BD + k], ec1);
            }
            float h0 = q0 + kb0 + ec0; h0 = h0 > 0.f ? h0 : NEG * h0;
            float h1 = q1 + kb1 + ec1; h1 = h1 > 0.f ? h1 : NEG * h1;
            float t0 = sum16(a0 * h0);
            float t1 = sum16(a1 * h1);
            float e0 = __expf(t0), e1 = __expf(t1);
            sum0 += e0; acc0 = fmaf(e0, vv0, acc0);
            sum1 += e1; acc1 = fmaf(e1, vv1, acc1);
        }
    }
    out[(size_t)n * CH + l]      = (end > start) ? acc0 / sum0 : 0.f;
    out[(size_t)n * CH + 64 + l] = (end > start) ? acc1 / sum1 : 0.f;
}

extern "C" void kernel_launch(void* const* d_in, const int* in_sizes, int n_in,
                              void* d_out, int out_size, void* d_ws, size_t ws_size,
                              hipStream_t stream)
{
    const float* senders   = (const float*)d_in[0];
    const float* receivers = (const float*)d_in[1];
    const int*   eidx      = (const int*)d_in[2];
    const float* eattr     = (const float*)d_in[3];
    const float* WQ  = (const float*)d_in[4];
    const float* WK  = (const float*)d_in[5];
    const float* WV  = (const float*)d_in[6];
    const float* WE  = (const float*)d_in[7];
    const float* att = (const float*)d_in[8];
    float* out = (float*)d_out;

    char* ws = (char*)d_ws;
    size_t off = 0;
    auto alloc = [&](size_t bytes) -> void* {
        void* p = ws + off;
        off += (bytes + 255) & ~(size_t)255;
        return p;
    };
    // Total ~20.7 MB (< 38.5 MB proven safe in R1; R2's 43.7 MB failed)
    float*          Qn     = (float*)alloc((size_t)NN * CH * 4);
    unsigned short* KB     = (unsigned short*)alloc((size_t)NN * CH * 2);
    float*          Vn     = (float*)alloc((size_t)NN * CH * 4);
    int*            counts = (int*)alloc((size_t)NN * 4);
    int*            starts = (int*)alloc((size_t)(NN + 1) * 4);
    int*            rank   = (int*)alloc((size_t)NE * 4);
    int2*           es     = (int2*)alloc((size_t)NE * 8);

    hipMemsetAsync(counts, 0, (size_t)NN * 4, stream);
    proj_hist_kernel<<<PROJ_BLOCKS + HIST_BLOCKS, 256, 0, stream>>>(
        senders, receivers, WQ, WK, WV, Qn, KB, Vn, eidx, counts, rank);
    scan_kernel<<<1, 1024, 0, stream>>>(counts, starts);
    scatter_kernel<<<HIST_BLOCKS, 256, 0, stream>>>(eidx, rank, starts, es);
    fused_kernel<<<NN / 4, 256, 0, stream>>>(es, starts, eattr, WE, att, Qn, KB, Vn, out);
}